// Round 3
// baseline (462.205 us; speedup 1.0000x reference)
//
#include <hip/hip_runtime.h>

// NearestNeighborTokenizer: ids = (min_c ||x - c||^2 <= 900) ? argmin_c : -1
// x: [8192, 512] fp32, codes: [16384, 512] fp32, out: [8192] int32
//
// fp16x3 MFMA GEMM: x,c scaled by 16, split into fp16 hi+lo planes,
// pre-swizzled in global memory into MFMA fragment order so the GEMM kernel
// stages tiles with global_load_lds(width=16) and reads fragments with
// ds_read_b128 conflict-free. dot = (hh + hl + lh)/256 in one fp32 acc.
// score = ||c||^2 - 2*dot; ||x||^2 added only at the final threshold test.
//
// R3: 4 blocks/CU (LDS 33KB: c2 read from global in epilogue, shuffle
// pre-reduce + 2KB scratch aliased into tiles), grid 1024 (NCHUNK=16),
// launch_bounds(256,4), prep kernels merged into one launch.

#define NTOK   8192
#define NCODES 16384
#define DDIM   512
#define NCHUNK 16
#define CHUNK  1024
#define DIST_THR 900.0f

typedef unsigned short u16;
typedef _Float16 half8 __attribute__((ext_vector_type(8)));
typedef float    f32x4 __attribute__((ext_vector_type(4)));

// ---------------- kernel 1: merged prep -------------------------------------
// blocks [0,2048): convert+swizzle x -> xh/xl
// blocks [2048,6144): convert+swizzle codes -> ch/cl
// blocks [6144,10240): c2[c] = ||codes[c]||^2 (one wave per code, fixed order)
//
// Swizzle: linear index c (8 halfs each):
//   r=c&15, q=(c>>4)&3, g=(c>>6)&7, kit=(c>>9)&15, tile=c>>13
//   row = tile*128 + g*16 + r ; k = kit*32 + q*8
// Each (tile,kit) is then a contiguous 8KB block in exactly the LDS fragment
// layout the GEMM wants (lane L <-> row base+(L&15), k-quad L>>4).
__device__ __forceinline__ void conv_body(const float* __restrict__ src,
                                          u16* __restrict__ dh,
                                          u16* __restrict__ dl, int c) {
    int r = c & 15, q = (c >> 4) & 3, g = (c >> 6) & 7, kit = (c >> 9) & 15;
    int tile = c >> 13;
    int row = tile * 128 + g * 16 + r;
    int k = kit * 32 + q * 8;
    const float* p = src + (size_t)row * DDIM + k;
    float4 v0 = *(const float4*)p;
    float4 v1 = *(const float4*)(p + 4);
    float vv[8] = {v0.x, v0.y, v0.z, v0.w, v1.x, v1.y, v1.z, v1.w};
    u16 hs[8], ls[8];
    #pragma unroll
    for (int j = 0; j < 8; ++j) {
        float sv = vv[j] * 16.0f;              // scale 16: keeps lo out of denorms
        _Float16 h = (_Float16)sv;
        float hf = (float)h;
        _Float16 l = (_Float16)(sv - hf);
        union { _Float16 f; u16 u; } uh, ul;
        uh.f = h; ul.f = l;
        hs[j] = uh.u; ls[j] = ul.u;
    }
    uint4 H, L;
    H.x = hs[0] | ((unsigned)hs[1] << 16); H.y = hs[2] | ((unsigned)hs[3] << 16);
    H.z = hs[4] | ((unsigned)hs[5] << 16); H.w = hs[6] | ((unsigned)hs[7] << 16);
    L.x = ls[0] | ((unsigned)ls[1] << 16); L.y = ls[2] | ((unsigned)ls[3] << 16);
    L.z = ls[4] | ((unsigned)ls[5] << 16); L.w = ls[6] | ((unsigned)ls[7] << 16);
    *(uint4*)(dh + (size_t)c * 8) = H;
    *(uint4*)(dl + (size_t)c * 8) = L;
}

__global__ __launch_bounds__(256) void nn_prep(const float* __restrict__ x,
                                               const float* __restrict__ codes,
                                               u16* __restrict__ xh, u16* __restrict__ xl,
                                               u16* __restrict__ ch, u16* __restrict__ cl,
                                               float* __restrict__ c2) {
    int b = blockIdx.x;
    if (b < 2048) {
        conv_body(x, xh, xl, b * 256 + threadIdx.x);
    } else if (b < 6144) {
        conv_body(codes, ch, cl, (b - 2048) * 256 + threadIdx.x);
    } else {
        int w = threadIdx.x >> 6;
        int lane = threadIdx.x & 63;
        int c = (b - 6144) * 4 + w;
        const float* p = codes + (size_t)c * DDIM + lane * 8;
        float4 v0 = *(const float4*)p;
        float4 v1 = *(const float4*)(p + 4);
        float s = v0.x*v0.x + v0.y*v0.y + v0.z*v0.z + v0.w*v0.w
                + v1.x*v1.x + v1.y*v1.y + v1.z*v1.z + v1.w*v1.w;
        #pragma unroll
        for (int off = 32; off > 0; off >>= 1) s += __shfl_down(s, off);
        if (lane == 0) c2[c] = s;
    }
}

// ---------------- kernel 2: fp16x3 MFMA GEMM + fused argmin -----------------
// grid = 64 m-tiles * 16 chunks, blockIdx.x = mtile*16 + chunk
// (chunk in low bits -> same-chunk blocks share an XCD, B-set 2MB in L2).
// Block: 128 tokens x 1024 codes (8 n-tiles of 128). 4 waves, each 64x64.
__global__ __launch_bounds__(256, 4) void nn_gemm(const u16* __restrict__ xh,
                                                  const u16* __restrict__ xl,
                                                  const u16* __restrict__ chh,
                                                  const u16* __restrict__ cll,
                                                  const float* __restrict__ c2,
                                                  float* __restrict__ pmin,
                                                  int* __restrict__ pid) {
    __shared__ __align__(16) char smem[32768];   // tiles; 2KB reduce scratch aliased
    const int tid = threadIdx.x;
    const int lane = tid & 63;
    const int wave = tid >> 6;
    const int wm = wave & 1;            // wave row  (64-row half)
    const int wn = wave >> 1;           // wave col  (64-col half)
    const int mtile = blockIdx.x >> 4;
    const int chunk = blockIdx.x & 15;
    const int m0 = mtile * 128;

    float mv[16];
    int   mi[16];
    #pragma unroll
    for (int s = 0; s < 16; ++s) { mv[s] = 3.4e38f; mi[s] = 0; }

    for (int nt = 0; nt < 8; ++nt) {
        f32x4 acc[4][4];
        #pragma unroll
        for (int i = 0; i < 4; ++i)
            #pragma unroll
            for (int j = 0; j < 4; ++j) acc[i][j] = (f32x4)0.0f;

        for (int kit = 0; kit < 16; ++kit) {
            // stage 32KB (4 plane-tiles of 8KB); each wave stages one plane
            const u16* gsrc;
            if (wave < 2) {
                size_t off = ((size_t)(mtile * 16 + kit)) * 4096;
                gsrc = (wave == 0 ? xh : xl) + off;
            } else {
                size_t off = ((size_t)((chunk * 8 + nt) * 16 + kit)) * 4096;
                gsrc = (wave == 2 ? chh : cll) + off;
            }
            char* ldsbase = smem + wave * 8192;
            #pragma unroll
            for (int jj = 0; jj < 8; ++jj) {
                __builtin_amdgcn_global_load_lds(
                    (const __attribute__((address_space(1))) void*)(gsrc + jj * 512 + lane * 8),
                    (__attribute__((address_space(3))) void*)(ldsbase + jj * 1024),
                    16, 0, 0);
            }
            __syncthreads();

            const char* Ah = smem;
            const char* Al = smem + 8192;
            const char* Bh = smem + 16384;
            const char* Bl = smem + 24576;
            half8 ah[4], al[4];
            #pragma unroll
            for (int i = 0; i < 4; ++i) {
                int g = wm * 4 + i;
                ah[i] = *(const half8*)(Ah + g * 1024 + lane * 16);
                al[i] = *(const half8*)(Al + g * 1024 + lane * 16);
            }
            #pragma unroll
            for (int j = 0; j < 4; ++j) {
                int g = wn * 4 + j;
                half8 bh = *(const half8*)(Bh + g * 1024 + lane * 16);
                half8 bl = *(const half8*)(Bl + g * 1024 + lane * 16);
                #pragma unroll
                for (int i = 0; i < 4; ++i) {
                    acc[i][j] = __builtin_amdgcn_mfma_f32_16x16x32_f16(ah[i], bh, acc[i][j], 0, 0, 0);
                    acc[i][j] = __builtin_amdgcn_mfma_f32_16x16x32_f16(ah[i], bl, acc[i][j], 0, 0, 0);
                    acc[i][j] = __builtin_amdgcn_mfma_f32_16x16x32_f16(al[i], bh, acc[i][j], 0, 0, 0);
                }
            }
            __syncthreads();
        }

        // epilogue: score = ||c||^2 - acc/128  (acc = 256 * x.c; -2/256)
        // candidates arrive in strictly increasing code id -> '<' keeps first.
        #pragma unroll
        for (int j = 0; j < 4; ++j) {
            int ncol = nt * 128 + wn * 64 + j * 16 + (lane & 15);
            int gid = chunk * CHUNK + ncol;
            float cv = c2[gid];
            #pragma unroll
            for (int i = 0; i < 4; ++i)
                #pragma unroll
                for (int r = 0; r < 4; ++r) {
                    float s = fmaf(acc[i][j][r], -0.0078125f, cv);
                    int slot = i * 4 + r;
                    if (s < mv[slot]) { mv[slot] = s; mi[slot] = gid; }
                }
        }
    }

    // shuffle pre-reduce across the 16 col-owner lanes (lane&15) per quad:
    // xor offsets 1,2,4,8 stay within the quad (lane>>4 fixed).
    #pragma unroll
    for (int off = 1; off < 16; off <<= 1) {
        #pragma unroll
        for (int s = 0; s < 16; ++s) {
            float ov = __shfl_xor(mv[s], off);
            int   oi = __shfl_xor(mi[s], off);
            if (ov < mv[s] || (ov == mv[s] && oi < mi[s])) { mv[s] = ov; mi[s] = oi; }
        }
    }
    // now 2 contributors per row (wn=0,1); scratch aliased onto tile memory
    // (trailing __syncthreads of the kit loop guarantees tiles are done).
    if ((lane & 15) == 0) {
        #pragma unroll
        for (int i = 0; i < 4; ++i)
            #pragma unroll
            for (int r = 0; r < 4; ++r) {
                int row = wm * 64 + i * 16 + (lane >> 4) * 4 + r;
                int2 e;
                e.x = __float_as_int(mv[i * 4 + r]);
                e.y = mi[i * 4 + r];
                *(int2*)(smem + (wn * 128 + row) * 8) = e;
            }
    }
    __syncthreads();
    if (tid < 128) {
        int2 e0 = *(const int2*)(smem + tid * 8);
        int2 e1 = *(const int2*)(smem + (128 + tid) * 8);
        float v0 = __int_as_float(e0.x), v1 = __int_as_float(e1.x);
        float bv = v0; int bi = e0.y;
        if (v1 < bv || (v1 == bv && e1.y < bi)) { bv = v1; bi = e1.y; }
        pmin[(size_t)(m0 + tid) * NCHUNK + chunk] = bv;
        pid [(size_t)(m0 + tid) * NCHUNK + chunk] = bi;
    }
}

// ---------------- kernel 3: finalize (one wave per token) -------------------
__global__ __launch_bounds__(256) void nn_fin(const float* __restrict__ x,
                                              const float* __restrict__ pmin,
                                              const int* __restrict__ pid,
                                              int* __restrict__ out) {
    int w = threadIdx.x >> 6;
    int lane = threadIdx.x & 63;
    int t = blockIdx.x * 4 + w;
    const float* p = x + (size_t)t * DDIM + lane * 8;
    float4 v0 = *(const float4*)p;
    float4 v1 = *(const float4*)(p + 4);
    float s = v0.x*v0.x + v0.y*v0.y + v0.z*v0.z + v0.w*v0.w
            + v1.x*v1.x + v1.y*v1.y + v1.z*v1.z + v1.w*v1.w;
    #pragma unroll
    for (int off = 32; off > 0; off >>= 1) s += __shfl_down(s, off);
    if (lane == 0) {
        const float* pm = pmin + (size_t)t * NCHUNK;
        const int*   pi = pid  + (size_t)t * NCHUNK;
        float bv = pm[0]; int bi = pi[0];
        #pragma unroll
        for (int c = 1; c < NCHUNK; ++c) {
            float v = pm[c]; int id = pi[c];
            if (v < bv || (v == bv && id < bi)) { bv = v; bi = id; }
        }
        float mind = s + bv;   // ||x||^2 + min(||c||^2 - 2 x.c)
        out[t] = (mind <= DIST_THR) ? bi : -1;
    }
}

extern "C" void kernel_launch(void* const* d_in, const int* in_sizes, int n_in,
                              void* d_out, int out_size, void* d_ws, size_t ws_size,
                              hipStream_t stream) {
    const float* x     = (const float*)d_in[0];
    const float* codes = (const float*)d_in[1];
    int* out = (int*)d_out;

    // workspace layout (bytes):
    //  xh 8MB | xl 8MB | ch 16MB | cl 16MB | c2 64KB | pmin 512KB | pid 512KB
    char* ws = (char*)d_ws;
    u16*   xh   = (u16*)(ws);
    u16*   xl   = (u16*)(ws + 8388608);
    u16*   chh  = (u16*)(ws + 16777216);
    u16*   cll  = (u16*)(ws + 33554432);
    float* c2   = (float*)(ws + 50331648);
    float* pmin = (float*)(ws + 50397184);
    int*   pid  = (int*)  (ws + 50921472);

    nn_prep<<<10240, 256, 0, stream>>>(x, codes, xh, xl, chh, cll, c2);
    nn_gemm<<<64 * NCHUNK, 256, 0, stream>>>(xh, xl, chh, cll, c2, pmin, pid);
    nn_fin<<<NTOK / 4, 256, 0, stream>>>(x, pmin, pid, out);
}

// Round 4
// 430.563 us; speedup vs baseline: 1.0735x; 1.0735x over previous
//
#include <hip/hip_runtime.h>

// NearestNeighborTokenizer: ids = (min_c ||x - c||^2 <= 900) ? argmin_c : -1
// x: [8192, 512] fp32, codes: [16384, 512] fp32, out: [8192] int32
//
// fp16x3 MFMA GEMM: x,c scaled by 16, split into fp16 hi+lo planes,
// pre-swizzled in global memory into MFMA fragment order so the GEMM kernel
// stages tiles with global_load_lds(width=16) and reads fragments with
// ds_read_b128 conflict-free. dot = (hh + hl + lh)/256 in one fp32 acc.
// score = ||c||^2 - 2*dot; ||x||^2 added only at the final threshold test.
//
// R4: LDS-BW-bound fix — wave tile 64x64 -> 64x128 (block 128x256, nt=4):
// LDS traffic 0.031 -> 0.023 B/FLOP. launch_bounds(256,2) so the 128-VGPR
// accumulator tile doesn't spill (R3's (256,4) caused 173MB of scratch).

#define NTOK   8192
#define NCODES 16384
#define DDIM   512
#define NCHUNK 16
#define CHUNK  1024
#define DIST_THR 900.0f

typedef unsigned short u16;
typedef _Float16 half8 __attribute__((ext_vector_type(8)));
typedef float    f32x4 __attribute__((ext_vector_type(4)));

// ---------------- kernel 1: merged prep -------------------------------------
// blocks [0,2048): convert+swizzle x -> xh/xl
// blocks [2048,6144): convert+swizzle codes -> ch/cl
// blocks [6144,10240): c2[c] = ||codes[c]||^2 (one wave per code)
//
// Swizzle: linear index c (8 halfs each):
//   r=c&15, q=(c>>4)&3, g=(c>>6)&7, kit=(c>>9)&15, tile=c>>13
//   row = tile*128 + g*16 + r ; k = kit*32 + q*8
// Each (tile,kit) is a contiguous 8KB block in exactly the LDS fragment
// layout the GEMM wants (lane L <-> row base+(L&15), k-quad L>>4).
__device__ __forceinline__ void conv_body(const float* __restrict__ src,
                                          u16* __restrict__ dh,
                                          u16* __restrict__ dl, int c) {
    int r = c & 15, q = (c >> 4) & 3, g = (c >> 6) & 7, kit = (c >> 9) & 15;
    int tile = c >> 13;
    int row = tile * 128 + g * 16 + r;
    int k = kit * 32 + q * 8;
    const float* p = src + (size_t)row * DDIM + k;
    float4 v0 = *(const float4*)p;
    float4 v1 = *(const float4*)(p + 4);
    float vv[8] = {v0.x, v0.y, v0.z, v0.w, v1.x, v1.y, v1.z, v1.w};
    u16 hs[8], ls[8];
    #pragma unroll
    for (int j = 0; j < 8; ++j) {
        float sv = vv[j] * 16.0f;              // scale 16: keeps lo out of denorms
        _Float16 h = (_Float16)sv;
        float hf = (float)h;
        _Float16 l = (_Float16)(sv - hf);
        union { _Float16 f; u16 u; } uh, ul;
        uh.f = h; ul.f = l;
        hs[j] = uh.u; ls[j] = ul.u;
    }
    uint4 H, L;
    H.x = hs[0] | ((unsigned)hs[1] << 16); H.y = hs[2] | ((unsigned)hs[3] << 16);
    H.z = hs[4] | ((unsigned)hs[5] << 16); H.w = hs[6] | ((unsigned)hs[7] << 16);
    L.x = ls[0] | ((unsigned)ls[1] << 16); L.y = ls[2] | ((unsigned)ls[3] << 16);
    L.z = ls[4] | ((unsigned)ls[5] << 16); L.w = ls[6] | ((unsigned)ls[7] << 16);
    *(uint4*)(dh + (size_t)c * 8) = H;
    *(uint4*)(dl + (size_t)c * 8) = L;
}

__global__ __launch_bounds__(256) void nn_prep(const float* __restrict__ x,
                                               const float* __restrict__ codes,
                                               u16* __restrict__ xh, u16* __restrict__ xl,
                                               u16* __restrict__ ch, u16* __restrict__ cl,
                                               float* __restrict__ c2) {
    int b = blockIdx.x;
    if (b < 2048) {
        conv_body(x, xh, xl, b * 256 + threadIdx.x);
    } else if (b < 6144) {
        conv_body(codes, ch, cl, (b - 2048) * 256 + threadIdx.x);
    } else {
        int w = threadIdx.x >> 6;
        int lane = threadIdx.x & 63;
        int c = (b - 6144) * 4 + w;
        const float* p = codes + (size_t)c * DDIM + lane * 8;
        float4 v0 = *(const float4*)p;
        float4 v1 = *(const float4*)(p + 4);
        float s = v0.x*v0.x + v0.y*v0.y + v0.z*v0.z + v0.w*v0.w
                + v1.x*v1.x + v1.y*v1.y + v1.z*v1.z + v1.w*v1.w;
        #pragma unroll
        for (int off = 32; off > 0; off >>= 1) s += __shfl_down(s, off);
        if (lane == 0) c2[c] = s;
    }
}

// ---------------- kernel 2: fp16x3 MFMA GEMM + fused argmin -----------------
// grid = 64 m-tiles * 16 chunks, blockIdx.x = mtile*16 + chunk
// (chunk in low bits -> same-chunk blocks spread across XCDs; B-set L2-local).
// Block: 128 tokens x 256 codes per nt (nt=4 over CHUNK=1024).
// 4 waves in 2x2: wave = wn*2+wm; each wave 64 rows x 128 cols.
// LDS 48KB/kit: Ah(8K)|Al(8K)|Bh(16K)|Bl(16K); 2KB reduce scratch aliased.
__global__ __launch_bounds__(256, 2) void nn_gemm(const u16* __restrict__ xh,
                                                  const u16* __restrict__ xl,
                                                  const u16* __restrict__ chh,
                                                  const u16* __restrict__ cll,
                                                  const float* __restrict__ c2,
                                                  float* __restrict__ pmin,
                                                  int* __restrict__ pid) {
    __shared__ __align__(16) char smem[49152];
    const int tid = threadIdx.x;
    const int lane = tid & 63;
    const int wave = tid >> 6;
    const int wm = wave & 1;            // 64-row half
    const int wn = wave >> 1;           // 128-col half
    const int mtile = blockIdx.x >> 4;
    const int chunk = blockIdx.x & 15;
    const int m0 = mtile * 128;

    float mv[16];
    int   mi[16];
    #pragma unroll
    for (int s = 0; s < 16; ++s) { mv[s] = 3.4e38f; mi[s] = 0; }

    for (int nt = 0; nt < 4; ++nt) {
        f32x4 acc[4][8];
        #pragma unroll
        for (int i = 0; i < 4; ++i)
            #pragma unroll
            for (int j = 0; j < 8; ++j) acc[i][j] = (f32x4)0.0f;

        for (int kit = 0; kit < 16; ++kit) {
            // stage 48KB as 48 x 1KB segments; wave stages g = wave*12+s:
            //  g in [0,8): Ah  | [8,16): Al | [16,32): Bh | [32,48): Bl
            #pragma unroll
            for (int s = 0; s < 12; ++s) {
                int g = wave * 12 + s;
                const u16* gsrc;
                if (g < 16) {
                    const u16* base = (g < 8) ? xh : xl;
                    gsrc = base + ((size_t)(mtile * 16 + kit)) * 4096
                                + (size_t)(g & 7) * 512;
                } else {
                    int h = g - 16;
                    const u16* base = (h < 16) ? chh : cll;
                    int ct = (h >> 3) & 1;          // which 128-col tile
                    gsrc = base + ((size_t)((chunk * 8 + nt * 2 + ct) * 16 + kit)) * 4096
                                + (size_t)(h & 7) * 512;
                }
                __builtin_amdgcn_global_load_lds(
                    (const __attribute__((address_space(1))) void*)(gsrc + lane * 8),
                    (__attribute__((address_space(3))) void*)(smem + g * 1024),
                    16, 0, 0);
            }
            __syncthreads();

            const char* Ah = smem;
            const char* Al = smem + 8192;
            const char* Bh = smem + 16384;
            const char* Bl = smem + 32768;
            half8 ah[4], al[4];
            #pragma unroll
            for (int i = 0; i < 4; ++i) {
                int g = wm * 4 + i;
                ah[i] = *(const half8*)(Ah + g * 1024 + lane * 16);
                al[i] = *(const half8*)(Al + g * 1024 + lane * 16);
            }
            #pragma unroll
            for (int j = 0; j < 8; ++j) {
                int g = wn * 8 + j;
                half8 bh = *(const half8*)(Bh + g * 1024 + lane * 16);
                half8 bl = *(const half8*)(Bl + g * 1024 + lane * 16);
                #pragma unroll
                for (int i = 0; i < 4; ++i) {
                    acc[i][j] = __builtin_amdgcn_mfma_f32_16x16x32_f16(ah[i], bh, acc[i][j], 0, 0, 0);
                    acc[i][j] = __builtin_amdgcn_mfma_f32_16x16x32_f16(ah[i], bl, acc[i][j], 0, 0, 0);
                    acc[i][j] = __builtin_amdgcn_mfma_f32_16x16x32_f16(al[i], bh, acc[i][j], 0, 0, 0);
                }
            }
            __syncthreads();
        }

        // epilogue: score = ||c||^2 - acc/128  (acc = 256 * x.c; -2/256)
        // candidates arrive in strictly increasing code id -> '<' keeps first.
        #pragma unroll
        for (int j = 0; j < 8; ++j) {
            int ncol = nt * 256 + wn * 128 + j * 16 + (lane & 15);
            int gid = chunk * CHUNK + ncol;
            float cv = c2[gid];
            #pragma unroll
            for (int i = 0; i < 4; ++i)
                #pragma unroll
                for (int r = 0; r < 4; ++r) {
                    float s = fmaf(acc[i][j][r], -0.0078125f, cv);
                    int slot = i * 4 + r;
                    if (s < mv[slot]) { mv[slot] = s; mi[slot] = gid; }
                }
        }
    }

    // shuffle pre-reduce across the 16 col-owner lanes (xor 1,2,4,8 stay
    // within the quad; lane>>4 is the row group and is preserved).
    #pragma unroll
    for (int off = 1; off < 16; off <<= 1) {
        #pragma unroll
        for (int s = 0; s < 16; ++s) {
            float ov = __shfl_xor(mv[s], off);
            int   oi = __shfl_xor(mi[s], off);
            if (ov < mv[s] || (ov == mv[s] && oi < mi[s])) { mv[s] = ov; mi[s] = oi; }
        }
    }
    // 2 contributors per row (wn=0,1); scratch aliased onto tile memory
    // (trailing __syncthreads of the kit loop guarantees tiles are done).
    if ((lane & 15) == 0) {
        #pragma unroll
        for (int i = 0; i < 4; ++i)
            #pragma unroll
            for (int r = 0; r < 4; ++r) {
                int row = wm * 64 + i * 16 + (lane >> 4) * 4 + r;
                int2 e;
                e.x = __float_as_int(mv[i * 4 + r]);
                e.y = mi[i * 4 + r];
                *(int2*)(smem + (wn * 128 + row) * 8) = e;
            }
    }
    __syncthreads();
    if (tid < 128) {
        int2 e0 = *(const int2*)(smem + tid * 8);
        int2 e1 = *(const int2*)(smem + (128 + tid) * 8);
        float v0 = __int_as_float(e0.x), v1 = __int_as_float(e1.x);
        float bv = v0; int bi = e0.y;
        if (v1 < bv || (v1 == bv && e1.y < bi)) { bv = v1; bi = e1.y; }
        pmin[(size_t)(m0 + tid) * NCHUNK + chunk] = bv;
        pid [(size_t)(m0 + tid) * NCHUNK + chunk] = bi;
    }
}

// ---------------- kernel 3: finalize (one wave per token) -------------------
__global__ __launch_bounds__(256) void nn_fin(const float* __restrict__ x,
                                              const float* __restrict__ pmin,
                                              const int* __restrict__ pid,
                                              int* __restrict__ out) {
    int w = threadIdx.x >> 6;
    int lane = threadIdx.x & 63;
    int t = blockIdx.x * 4 + w;
    const float* p = x + (size_t)t * DDIM + lane * 8;
    float4 v0 = *(const float4*)p;
    float4 v1 = *(const float4*)(p + 4);
    float s = v0.x*v0.x + v0.y*v0.y + v0.z*v0.z + v0.w*v0.w
            + v1.x*v1.x + v1.y*v1.y + v1.z*v1.z + v1.w*v1.w;
    #pragma unroll
    for (int off = 32; off > 0; off >>= 1) s += __shfl_down(s, off);
    if (lane == 0) {
        const float* pm = pmin + (size_t)t * NCHUNK;
        const int*   pi = pid  + (size_t)t * NCHUNK;
        float bv = pm[0]; int bi = pi[0];
        #pragma unroll
        for (int c = 1; c < NCHUNK; ++c) {
            float v = pm[c]; int id = pi[c];
            if (v < bv || (v == bv && id < bi)) { bv = v; bi = id; }
        }
        float mind = s + bv;   // ||x||^2 + min(||c||^2 - 2 x.c)
        out[t] = (mind <= DIST_THR) ? bi : -1;
    }
}

extern "C" void kernel_launch(void* const* d_in, const int* in_sizes, int n_in,
                              void* d_out, int out_size, void* d_ws, size_t ws_size,
                              hipStream_t stream) {
    const float* x     = (const float*)d_in[0];
    const float* codes = (const float*)d_in[1];
    int* out = (int*)d_out;

    // workspace layout (bytes):
    //  xh 8MB | xl 8MB | ch 16MB | cl 16MB | c2 64KB | pmin 512KB | pid 512KB
    char* ws = (char*)d_ws;
    u16*   xh   = (u16*)(ws);
    u16*   xl   = (u16*)(ws + 8388608);
    u16*   chh  = (u16*)(ws + 16777216);
    u16*   cll  = (u16*)(ws + 33554432);
    float* c2   = (float*)(ws + 50331648);
    float* pmin = (float*)(ws + 50397184);
    int*   pid  = (int*)  (ws + 50921472);

    nn_prep<<<10240, 256, 0, stream>>>(x, codes, xh, xl, chh, cll, c2);
    nn_gemm<<<64 * NCHUNK, 256, 0, stream>>>(xh, xl, chh, cll, c2, pmin, pid);
    nn_fin<<<NTOK / 4, 256, 0, stream>>>(x, pmin, pid, out);
}

// Round 5
// 408.331 us; speedup vs baseline: 1.1319x; 1.0544x over previous
//
#include <hip/hip_runtime.h>

// NearestNeighborTokenizer: ids = (min_c ||x - c||^2 <= 900) ? argmin_c : -1
// x: [8192, 512] fp32, codes: [16384, 512] fp32, out: [8192] int32
//
// fp16x3 MFMA GEMM: x,c scaled by 16, split into fp16 hi+lo planes,
// pre-swizzled in global memory into MFMA fragment order. dot =
// (hh + hl + lh)/256 in one fp32 acc. score = ||c||^2 - 2*dot.
//
// R5: software-pipelined K-loop. 512-thread block, 256x256 tile, BK=32,
// LDS double-buffer 2x64KB. Inline-asm "s_waitcnt vmcnt(8); s_barrier"
// keeps the current iteration's 8 global_load_lds in flight across the
// barrier (HIP __syncthreads would emit vmcnt(0) and drain them — the
// structural ~40% stall of R2-R4). Grid 256 = exactly 1 block/CU.

#define NTOK   8192
#define NCODES 16384
#define DDIM   512
#define NCHUNK 8
#define CHUNK  2048
#define DIST_THR 900.0f

typedef unsigned short u16;
typedef _Float16 half8 __attribute__((ext_vector_type(8)));
typedef float    f32x4 __attribute__((ext_vector_type(4)));

// ---------------- kernel 1: merged prep -------------------------------------
// blocks [0,2048): convert+swizzle x -> xh/xl
// blocks [2048,6144): convert+swizzle codes -> ch/cl
// blocks [6144,10240): c2[c] = ||codes[c]||^2 (one wave per code)
//
// Swizzle: linear index c (8 halfs each):
//   r=c&15, q=(c>>4)&3, g=(c>>6)&7, kit=(c>>9)&15, tile=c>>13
//   row = tile*128 + g*16 + r ; k = kit*32 + q*8
// Each (tile,kit) is a contiguous 8KB block in exactly the LDS fragment
// layout the GEMM wants (lane L <-> row base+(L&15), k-quad L>>4).
__device__ __forceinline__ void conv_body(const float* __restrict__ src,
                                          u16* __restrict__ dh,
                                          u16* __restrict__ dl, int c) {
    int r = c & 15, q = (c >> 4) & 3, g = (c >> 6) & 7, kit = (c >> 9) & 15;
    int tile = c >> 13;
    int row = tile * 128 + g * 16 + r;
    int k = kit * 32 + q * 8;
    const float* p = src + (size_t)row * DDIM + k;
    float4 v0 = *(const float4*)p;
    float4 v1 = *(const float4*)(p + 4);
    float vv[8] = {v0.x, v0.y, v0.z, v0.w, v1.x, v1.y, v1.z, v1.w};
    u16 hs[8], ls[8];
    #pragma unroll
    for (int j = 0; j < 8; ++j) {
        float sv = vv[j] * 16.0f;              // scale 16: keeps lo out of denorms
        _Float16 h = (_Float16)sv;
        float hf = (float)h;
        _Float16 l = (_Float16)(sv - hf);
        union { _Float16 f; u16 u; } uh, ul;
        uh.f = h; ul.f = l;
        hs[j] = uh.u; ls[j] = ul.u;
    }
    uint4 H, L;
    H.x = hs[0] | ((unsigned)hs[1] << 16); H.y = hs[2] | ((unsigned)hs[3] << 16);
    H.z = hs[4] | ((unsigned)hs[5] << 16); H.w = hs[6] | ((unsigned)hs[7] << 16);
    L.x = ls[0] | ((unsigned)ls[1] << 16); L.y = ls[2] | ((unsigned)ls[3] << 16);
    L.z = ls[4] | ((unsigned)ls[5] << 16); L.w = ls[6] | ((unsigned)ls[7] << 16);
    *(uint4*)(dh + (size_t)c * 8) = H;
    *(uint4*)(dl + (size_t)c * 8) = L;
}

__global__ __launch_bounds__(256) void nn_prep(const float* __restrict__ x,
                                               const float* __restrict__ codes,
                                               u16* __restrict__ xh, u16* __restrict__ xl,
                                               u16* __restrict__ ch, u16* __restrict__ cl,
                                               float* __restrict__ c2) {
    int b = blockIdx.x;
    if (b < 2048) {
        conv_body(x, xh, xl, b * 256 + threadIdx.x);
    } else if (b < 6144) {
        conv_body(codes, ch, cl, (b - 2048) * 256 + threadIdx.x);
    } else {
        int w = threadIdx.x >> 6;
        int lane = threadIdx.x & 63;
        int c = (b - 6144) * 4 + w;
        const float* p = codes + (size_t)c * DDIM + lane * 8;
        float4 v0 = *(const float4*)p;
        float4 v1 = *(const float4*)(p + 4);
        float s = v0.x*v0.x + v0.y*v0.y + v0.z*v0.z + v0.w*v0.w
                + v1.x*v1.x + v1.y*v1.y + v1.z*v1.z + v1.w*v1.w;
        #pragma unroll
        for (int off = 32; off > 0; off >>= 1) s += __shfl_down(s, off);
        if (lane == 0) c2[c] = s;
    }
}

// ---------------- kernel 2: pipelined fp16x3 MFMA GEMM + fused argmin -------
// grid = 32 mtiles * 8 chunks, blockIdx.x = mtile*8 + chunk (chunk<->XCD:
// each XCD's 32 co-resident blocks share one 4MB B-set = its L2).
// Block: 512 threads = 8 waves (wm=wave&3 row-quarter, wn=wave>>2 col-half);
// block tile 256 rows x 256 cols per nt (nt=0..7 over CHUNK=2048).
// Wave tile 64x128. LDS: 2 x 64KB ping-pong [Ah 16K|Al 16K|Bh 16K|Bl 16K].
__global__ __launch_bounds__(512, 2) void nn_gemm(const u16* __restrict__ xh,
                                                  const u16* __restrict__ xl,
                                                  const u16* __restrict__ chh,
                                                  const u16* __restrict__ cll,
                                                  const float* __restrict__ c2,
                                                  float* __restrict__ pmin,
                                                  int* __restrict__ pid) {
    __shared__ __align__(16) char smem[131072];
    const int tid = threadIdx.x;
    const int lane = tid & 63;
    const int wave = tid >> 6;          // 0..7
    const int wm = wave & 3;            // 64-row quarter
    const int wn = wave >> 2;           // 128-col half
    const int mtile = blockIdx.x >> 3;  // 0..31
    const int chunk = blockIdx.x & 7;   // 0..7
    const int m0 = mtile * 256;

    // wave-static staging role: plane = wave>>1 (0 Ah,1 Al,2 Bh,3 Bl),
    // tsub = wave&1 selects which 128-row/col subtile of the 256-tile.
    const int plane = wave >> 1;
    const int tsub  = wave & 1;
    const bool isA = (plane < 2);
    const u16* gbase;
    if (plane == 0)      gbase = xh  + ((size_t)(mtile * 2 + tsub) * 16) * 4096;
    else if (plane == 1) gbase = xl  + ((size_t)(mtile * 2 + tsub) * 16) * 4096;
    else if (plane == 2) gbase = chh + ((size_t)(chunk * 16 + tsub) * 16) * 4096;
    else                 gbase = cll + ((size_t)(chunk * 16 + tsub) * 16) * 4096;
    gbase += lane * 8;
    // LDS dst region for this wave: plane p at p*16KB, subtile at tsub*8KB
    const int ldsoff = wave * 8192;     // == plane*16384 + tsub*8192

    float mv[16];
    int   mi[16];
    #pragma unroll
    for (int s = 0; s < 16; ++s) { mv[s] = 3.4e38f; mi[s] = 0; }

    f32x4 acc[4][8];
    #pragma unroll
    for (int i = 0; i < 4; ++i)
        #pragma unroll
        for (int j = 0; j < 8; ++j) acc[i][j] = (f32x4)0.0f;

    // stage iteration it2 = nt*16 + kit into buffer (it2&1)
    auto stage = [&](int it2) {
        int kit2 = it2 & 15, nt2 = it2 >> 4;
        size_t off = (size_t)(isA ? kit2 : nt2 * 32 + kit2) * 4096;
        const u16* src = gbase + off;
        char* dst = smem + (size_t)(it2 & 1) * 65536 + ldsoff;
        #pragma unroll
        for (int s = 0; s < 8; ++s)
            __builtin_amdgcn_global_load_lds(
                (const __attribute__((address_space(1))) void*)(src + s * 512),
                (__attribute__((address_space(3))) void*)(dst + s * 1024),
                16, 0, 0);
    };

    stage(0);
    for (int it = 0; it < 128; ++it) {
        if (it < 127) {
            stage(it + 1);
            // wait only for LAST iteration's 8 loads; this iteration's 8
            // stay in flight across the barrier (the whole point of R5).
            asm volatile("s_waitcnt vmcnt(8)\n\ts_barrier" ::: "memory");
        } else {
            asm volatile("s_waitcnt vmcnt(0)\n\ts_barrier" ::: "memory");
        }

        const char* cur = smem + (size_t)(it & 1) * 65536;
        half8 ah[4], al[4];
        #pragma unroll
        for (int i = 0; i < 4; ++i) {
            int g = wm * 4 + i;                 // A group (16 rows each)
            ah[i] = *(const half8*)(cur +         g * 1024 + lane * 16);
            al[i] = *(const half8*)(cur + 16384 + g * 1024 + lane * 16);
        }
        #pragma unroll
        for (int j = 0; j < 8; ++j) {
            int g = wn * 8 + j;                 // B group (16 cols each)
            half8 bh = *(const half8*)(cur + 32768 + g * 1024 + lane * 16);
            half8 bl = *(const half8*)(cur + 49152 + g * 1024 + lane * 16);
            #pragma unroll
            for (int i = 0; i < 4; ++i) {
                acc[i][j] = __builtin_amdgcn_mfma_f32_16x16x32_f16(ah[i], bh, acc[i][j], 0, 0, 0);
                acc[i][j] = __builtin_amdgcn_mfma_f32_16x16x32_f16(ah[i], bl, acc[i][j], 0, 0, 0);
                acc[i][j] = __builtin_amdgcn_mfma_f32_16x16x32_f16(al[i], bh, acc[i][j], 0, 0, 0);
            }
        }

        if ((it & 15) == 15) {
            // epilogue for nt: score = ||c||^2 - acc/128 (acc = 256 * x.c).
            // candidates arrive in increasing code id -> '<' keeps first.
            int nt = it >> 4;
            #pragma unroll
            for (int j = 0; j < 8; ++j) {
                int ncol = nt * 256 + wn * 128 + j * 16 + (lane & 15);
                int gid = chunk * CHUNK + ncol;
                float cv = c2[gid];
                #pragma unroll
                for (int i = 0; i < 4; ++i)
                    #pragma unroll
                    for (int r = 0; r < 4; ++r) {
                        float s = fmaf(acc[i][j][r], -0.0078125f, cv);
                        int slot = i * 4 + r;
                        if (s < mv[slot]) { mv[slot] = s; mi[slot] = gid; }
                    }
            }
            #pragma unroll
            for (int i = 0; i < 4; ++i)
                #pragma unroll
                for (int j = 0; j < 8; ++j) acc[i][j] = (f32x4)0.0f;
        }
        // release barrier: all waves done reading `cur` before it is
        // re-staged at the top of the next iteration.
        asm volatile("s_barrier" ::: "memory");
    }

    // shuffle pre-reduce across the 16 col-owner lanes (xor 1,2,4,8 stay
    // within the quad; lane>>4 = row quad is preserved).
    #pragma unroll
    for (int off = 1; off < 16; off <<= 1) {
        #pragma unroll
        for (int s = 0; s < 16; ++s) {
            float ov = __shfl_xor(mv[s], off);
            int   oi = __shfl_xor(mi[s], off);
            if (ov < mv[s] || (ov == mv[s] && oi < mi[s])) { mv[s] = ov; mi[s] = oi; }
        }
    }
    // 2 contributors per row (wn=0,1); 4KB scratch aliases buf0 (all tile
    // reads finished at the final barrier above; it=127 read buf1 anyway).
    if ((lane & 15) == 0) {
        #pragma unroll
        for (int i = 0; i < 4; ++i)
            #pragma unroll
            for (int r = 0; r < 4; ++r) {
                int row = wm * 64 + i * 16 + (lane >> 4) * 4 + r;
                int2 e;
                e.x = __float_as_int(mv[i * 4 + r]);
                e.y = mi[i * 4 + r];
                *(int2*)(smem + (wn * 256 + row) * 8) = e;
            }
    }
    __syncthreads();
    if (tid < 256) {
        int2 e0 = *(const int2*)(smem + tid * 8);
        int2 e1 = *(const int2*)(smem + (256 + tid) * 8);
        float v0 = __int_as_float(e0.x), v1 = __int_as_float(e1.x);
        float bv = v0; int bi = e0.y;
        if (v1 < bv || (v1 == bv && e1.y < bi)) { bv = v1; bi = e1.y; }
        pmin[(size_t)(m0 + tid) * NCHUNK + chunk] = bv;
        pid [(size_t)(m0 + tid) * NCHUNK + chunk] = bi;
    }
}

// ---------------- kernel 3: finalize (one wave per token) -------------------
__global__ __launch_bounds__(256) void nn_fin(const float* __restrict__ x,
                                              const float* __restrict__ pmin,
                                              const int* __restrict__ pid,
                                              int* __restrict__ out) {
    int w = threadIdx.x >> 6;
    int lane = threadIdx.x & 63;
    int t = blockIdx.x * 4 + w;
    const float* p = x + (size_t)t * DDIM + lane * 8;
    float4 v0 = *(const float4*)p;
    float4 v1 = *(const float4*)(p + 4);
    float s = v0.x*v0.x + v0.y*v0.y + v0.z*v0.z + v0.w*v0.w
            + v1.x*v1.x + v1.y*v1.y + v1.z*v1.z + v1.w*v1.w;
    #pragma unroll
    for (int off = 32; off > 0; off >>= 1) s += __shfl_down(s, off);
    if (lane == 0) {
        const float* pm = pmin + (size_t)t * NCHUNK;
        const int*   pi = pid  + (size_t)t * NCHUNK;
        float bv = pm[0]; int bi = pi[0];
        #pragma unroll
        for (int c = 1; c < NCHUNK; ++c) {
            float v = pm[c]; int id = pi[c];
            if (v < bv || (v == bv && id < bi)) { bv = v; bi = id; }
        }
        float mind = s + bv;   // ||x||^2 + min(||c||^2 - 2 x.c)
        out[t] = (mind <= DIST_THR) ? bi : -1;
    }
}

extern "C" void kernel_launch(void* const* d_in, const int* in_sizes, int n_in,
                              void* d_out, int out_size, void* d_ws, size_t ws_size,
                              hipStream_t stream) {
    const float* x     = (const float*)d_in[0];
    const float* codes = (const float*)d_in[1];
    int* out = (int*)d_out;

    // workspace layout (bytes):
    //  xh 8MB | xl 8MB | ch 16MB | cl 16MB | c2 64KB | pmin 256KB | pid 256KB
    char* ws = (char*)d_ws;
    u16*   xh   = (u16*)(ws);
    u16*   xl   = (u16*)(ws + 8388608);
    u16*   chh  = (u16*)(ws + 16777216);
    u16*   cll  = (u16*)(ws + 33554432);
    float* c2   = (float*)(ws + 50331648);
    float* pmin = (float*)(ws + 50397184);
    int*   pid  = (int*)  (ws + 50659328);

    nn_prep<<<10240, 256, 0, stream>>>(x, codes, xh, xl, chh, cll, c2);
    nn_gemm<<<32 * NCHUNK, 512, 0, stream>>>(xh, xl, chh, cll, c2, pmin, pid);
    nn_fin<<<NTOK / 4, 256, 0, stream>>>(x, pmin, pid, out);
}